// Round 11
// baseline (238.750 us; speedup 1.0000x reference)
//
#include <hip/hip_runtime.h>
#include <hip/hip_bf16.h>
#include <stdint.h>

#define B_SZ 4
#define SEQ  2048
#define DM   1024
#define NH   16
#define HD   64
#define MTOT (B_SZ*SEQ)          // 8192
#define QS_LOG2E 0.18033688011112042f
#define M0SHIFT  24.0f

typedef __attribute__((ext_vector_type(8))) short bf16x8;
typedef __attribute__((ext_vector_type(4))) float f32x4;

#if __has_builtin(__builtin_amdgcn_exp2f)
__device__ __forceinline__ float fexp2(float x) { return __builtin_amdgcn_exp2f(x); }
#else
__device__ __forceinline__ float fexp2(float x) {
  float r; asm("v_exp_f32 %0, %1" : "=v"(r) : "v"(x)); return r;
}
#endif

__device__ __forceinline__ unsigned short f2b(float f) {
  union { float f; unsigned int i; } v; v.f = f;
  unsigned int r = v.i + 0x7fffu + ((v.i >> 16) & 1u);
  return (unsigned short)(r >> 16);
}

#define GPTR __attribute__((address_space(1)))
#define LPTR __attribute__((address_space(3)))
__device__ __forceinline__ void gl_lds16(const void* g, void* l) {
  __builtin_amdgcn_global_load_lds((GPTR const unsigned int*)g,
                                   (LPTR unsigned int*)l, 16, 0, 0);
}

// ---------------- fused f32 -> bf16 bulk converts ---------------------------
__device__ __forceinline__ void conv_body(const float* __restrict__ in,
                                          unsigned short* __restrict__ out, int n) {
  int i = (blockIdx.x * 256 + threadIdx.x) * 8;
  int stride = gridDim.x * 256 * 8;
  for (; i < n; i += stride) {
    float4 x = *(const float4*)(in + i);
    float4 y = *(const float4*)(in + i + 4);
    ushort4 u0; u0.x = f2b(x.x); u0.y = f2b(x.y); u0.z = f2b(x.z); u0.w = f2b(x.w);
    ushort4 u1; u1.x = f2b(y.x); u1.y = f2b(y.y); u1.z = f2b(y.z); u1.w = f2b(y.w);
    *(ushort4*)(out + i)     = u0;
    *(ushort4*)(out + i + 4) = u1;
  }
}
__global__ __launch_bounds__(256) void conv7(
    const float* __restrict__ q, const float* __restrict__ k, const float* __restrict__ v,
    const float* __restrict__ Wq, const float* __restrict__ Wk,
    const float* __restrict__ Wv, const float* __restrict__ Wo,
    unsigned short* __restrict__ oq, unsigned short* __restrict__ ok,
    unsigned short* __restrict__ ov, unsigned short* __restrict__ oWq,
    unsigned short* __restrict__ oWk, unsigned short* __restrict__ oWv,
    unsigned short* __restrict__ oWo, int nAct, int nW) {
  const int z = blockIdx.z;
  const float* in = (z == 0) ? q : (z == 1) ? k : (z == 2) ? v
                  : (z == 3) ? Wq : (z == 4) ? Wk : (z == 5) ? Wv : Wo;
  unsigned short* out = (z == 0) ? oq : (z == 1) ? ok : (z == 2) ? ov
                      : (z == 3) ? oWq : (z == 4) ? oWk : (z == 5) ? oWv : oWo;
  conv_body(in, out, (z < 3) ? nAct : nW);
}
__global__ __launch_bounds__(256) void conv4(const float* __restrict__ a,
                                             const float* __restrict__ b,
                                             const float* __restrict__ c,
                                             const float* __restrict__ d,
                                             unsigned short* __restrict__ oa,
                                             unsigned short* __restrict__ ob,
                                             unsigned short* __restrict__ oc,
                                             unsigned short* __restrict__ od,
                                             int n) {
  const float* in = (blockIdx.z == 0) ? a : (blockIdx.z == 1) ? b
                  : (blockIdx.z == 2) ? c : d;
  unsigned short* out = (blockIdx.z == 0) ? oa : (blockIdx.z == 1) ? ob
                      : (blockIdx.z == 2) ? oc : od;
  conv_body(in, out, n);
}

// ---------------- LDS staging (XOR swizzle) ---------------------------------
// element(row,col) at lds[(row*64+col) ^ ((row&7)<<3)]
__device__ __forceinline__ void stage_glds(const unsigned short* __restrict__ src,
                                           int ld, char* lds, int t) {
  const int gbase = t & ~63;
  const int lane  = t & 63;
  #pragma unroll
  for (int i = 0; i < 4; ++i) {
    int gb  = i*256 + gbase;
    int g   = gb + lane;
    int row = g >> 3;
    int cg  = (g & 7) ^ (row & 7);
    gl_lds16(src + (size_t)row*ld + cg*8, lds + (size_t)gb*16);
  }
}
// NCH = number of 16B chunks / 512 (tile elems / 4096): A(256x64)=4, B(128x64)=2
template<int NI>
__device__ __forceinline__ void stage_glds512(const unsigned short* __restrict__ src,
                                              int ld, char* lds, int t) {
  const int gbase = t & ~63;
  const int lane  = t & 63;
  #pragma unroll
  for (int i = 0; i < NI; ++i) {
    int gb  = i*512 + gbase;
    int g   = gb + lane;
    int row = g >> 3;
    int cg  = (g & 7) ^ (row & 7);
    gl_lds16(src + (size_t)row*ld + cg*8, lds + (size_t)gb*16);
  }
}
__device__ __forceinline__ void stage_f32(const float* __restrict__ src, int ld,
                                          unsigned short* lds, int t) {
  #pragma unroll
  for (int i = 0; i < 8; ++i) {
    int e   = i*1024 + t*4;
    int row = e >> 6;
    int c4  = (e >> 2) & 15;
    float4 f = *(const float4*)(src + (size_t)row*ld + c4*4);
    ushort4 u;
    u.x = f2b(f.x); u.y = f2b(f.y); u.z = f2b(f.z); u.w = f2b(f.w);
    int hi = (row*64 + c4*4) ^ ((row & 7) << 3);
    *(ushort4*)&lds[hi] = u;
  }
}

// ---------------------------------------------------------------------------
// 256x128-tile GEMM core, 512 threads / 8 waves (4m x 2n). Per wave: the
// VALIDATED 64x64 inner loop (identical frag/acc layout to the 128^2 kernel);
// staged bytes per FLOP 2.7x lower, barrier-drains per FLOP halved.
// C[m,n] = (sum_k X[m,k]*W[n,k] + bias[n]) * oscale
// ---------------------------------------------------------------------------
template<int OUTF32>
__device__ __forceinline__ void gemm_core_256(
    const unsigned short* __restrict__ X, const unsigned short* __restrict__ W,
    const float* __restrict__ bias, void* __restrict__ C,
    float oscale, int m0, int n0, int t,
    unsigned short* As, unsigned short* Bs)
{
  const int lane = t & 63;
  const int w    = t >> 6;          // 0..7
  const int wm   = w >> 1;          // 0..3 (64-row strip)
  const int wn   = w & 1;           // 0..1 (64-col strip)

  f32x4 acc[4][4] = {};

  for (int k0 = 0; k0 < DM; k0 += 64) {
    __syncthreads();
    stage_glds512<4>(X + (size_t)m0*DM + k0, DM, (char*)As, t);  // 256x64
    stage_glds512<2>(W + (size_t)n0*DM + k0, DM, (char*)Bs, t);  // 128x64
    __syncthreads();

    #pragma unroll
    for (int kk = 0; kk < 2; ++kk) {
      bf16x8 af[4], bfr[4];
      #pragma unroll
      for (int mt = 0; mt < 4; ++mt) {
        int r  = wm*64 + mt*16 + (lane & 15);
        int hi = (r*64 + kk*32 + (lane >> 4)*8) ^ ((r & 7) << 3);
        af[mt] = *(const bf16x8*)&As[hi];
      }
      #pragma unroll
      for (int nt = 0; nt < 4; ++nt) {
        int r  = wn*64 + nt*16 + (lane & 15);
        int hi = (r*64 + kk*32 + (lane >> 4)*8) ^ ((r & 7) << 3);
        bfr[nt] = *(const bf16x8*)&Bs[hi];
      }
      #pragma unroll
      for (int mt = 0; mt < 4; ++mt)
        #pragma unroll
        for (int nt = 0; nt < 4; ++nt)
          acc[mt][nt] = __builtin_amdgcn_mfma_f32_16x16x32_bf16(
              af[mt], bfr[nt], acc[mt][nt], 0, 0, 0);
    }
  }

  #pragma unroll
  for (int nt = 0; nt < 4; ++nt) {
    int col = n0 + wn*64 + nt*16 + (lane & 15);
    float bv = bias[col];
    #pragma unroll
    for (int mt = 0; mt < 4; ++mt) {
      #pragma unroll
      for (int j = 0; j < 4; ++j) {
        int rrow = m0 + wm*64 + mt*16 + (lane >> 4)*4 + j;
        float val = (acc[mt][nt][j] + bv) * oscale;
        if (OUTF32) ((float*)C)[(size_t)rrow*DM + col] = val;
        else        ((unsigned short*)C)[(size_t)rrow*DM + col] = f2b(val);
      }
    }
  }
}

// fused Q/K/V projection: grid (DM/128, MTOT/256, 3)
__global__ __launch_bounds__(512, 1) void gemm_qkv256(
    const unsigned short* __restrict__ Xb, const unsigned short* __restrict__ Wb,
    const float* __restrict__ b0, const float* __restrict__ b1,
    const float* __restrict__ b2, unsigned short* __restrict__ Cb, float os0)
{
  __shared__ __align__(16) unsigned short As[256*64];
  __shared__ __align__(16) unsigned short Bs[128*64];
  const int z = blockIdx.z;
  const size_t MD  = (size_t)MTOT * DM;
  const size_t WSZ = (size_t)DM * DM;
  const float* bias = (z == 0) ? b0 : (z == 1) ? b1 : b2;
  gemm_core_256<0>(Xb + (size_t)z*MD, Wb + (size_t)z*WSZ, bias,
                   (void*)(Cb + (size_t)z*MD), (z == 0) ? os0 : 1.0f,
                   blockIdx.y * 256, blockIdx.x * 128, threadIdx.x, As, Bs);
}

// O projection: grid (DM/128, MTOT/256), f32 out
__global__ __launch_bounds__(512, 1) void gemm_o256(
    const unsigned short* __restrict__ X, const unsigned short* __restrict__ W,
    const float* __restrict__ bias, float* __restrict__ C)
{
  __shared__ __align__(16) unsigned short As[256*64];
  __shared__ __align__(16) unsigned short Bs[128*64];
  gemm_core_256<1>(X, W, bias, (void*)C, 1.0f,
                   blockIdx.y * 256, blockIdx.x * 128, threadIdx.x, As, Bs);
}

// general single GEMM (fallback paths), 128^2
template<int AF32, int BF32, int OUTF32>
__global__ __launch_bounds__(256, 2) void gemm_bias(
    const void* __restrict__ Xv,
    const void* __restrict__ Wv,
    const float* __restrict__ bias,
    void* __restrict__ Cout,
    int M, int N, int Kd, float oscale)
{
  __shared__ __align__(16) unsigned short As[128*64];
  __shared__ __align__(16) unsigned short Bs[128*64];
  const int t    = threadIdx.x;
  const int lane = t & 63;
  const int w    = t >> 6;
  const int wm   = w >> 1, wn = w & 1;
  const int m0   = blockIdx.y * 128;
  const int n0   = blockIdx.x * 128;

  f32x4 acc[4][4] = {};

  for (int k0 = 0; k0 < Kd; k0 += 64) {
    __syncthreads();
    if (AF32) stage_f32((const float*)Xv + (size_t)m0*Kd + k0, Kd, As, t);
    else      stage_glds((const unsigned short*)Xv + (size_t)m0*Kd + k0, Kd, (char*)As, t);
    if (BF32) stage_f32((const float*)Wv + (size_t)n0*Kd + k0, Kd, Bs, t);
    else      stage_glds((const unsigned short*)Wv + (size_t)n0*Kd + k0, Kd, (char*)Bs, t);
    __syncthreads();

    #pragma unroll
    for (int kk = 0; kk < 2; ++kk) {
      bf16x8 af[4], bfr[4];
      #pragma unroll
      for (int mt = 0; mt < 4; ++mt) {
        int r  = wm*64 + mt*16 + (lane & 15);
        int hi = (r*64 + kk*32 + (lane >> 4)*8) ^ ((r & 7) << 3);
        af[mt] = *(const bf16x8*)&As[hi];
      }
      #pragma unroll
      for (int nt = 0; nt < 4; ++nt) {
        int r  = wn*64 + nt*16 + (lane & 15);
        int hi = (r*64 + kk*32 + (lane >> 4)*8) ^ ((r & 7) << 3);
        bfr[nt] = *(const bf16x8*)&Bs[hi];
      }
      #pragma unroll
      for (int mt = 0; mt < 4; ++mt)
        #pragma unroll
        for (int nt = 0; nt < 4; ++nt)
          acc[mt][nt] = __builtin_amdgcn_mfma_f32_16x16x32_bf16(
              af[mt], bfr[nt], acc[mt][nt], 0, 0, 0);
    }
  }

  #pragma unroll
  for (int nt = 0; nt < 4; ++nt) {
    int col = n0 + wn*64 + nt*16 + (lane & 15);
    float bv = bias[col];
    #pragma unroll
    for (int mt = 0; mt < 4; ++mt) {
      #pragma unroll
      for (int j = 0; j < 4; ++j) {
        int rrow = m0 + wm*64 + mt*16 + (lane >> 4)*4 + j;
        float val = (acc[mt][nt][j] + bv) * oscale;
        if (OUTF32)
          ((float*)Cout)[(size_t)rrow*N + col] = val;
        else
          ((unsigned short*)Cout)[(size_t)rrow*N + col] = f2b(val);
      }
    }
  }
}

// ---------------------------------------------------------------------------
// Flash attention fwd (frozen; R10: 97.7us, FETCH 24.6MB, VGPR=100).
// ---------------------------------------------------------------------------
__global__ __launch_bounds__(256, 2) void attn_fwd(
    const unsigned short* __restrict__ Qb,
    const unsigned short* __restrict__ Kb,
    const unsigned short* __restrict__ Vb,
    unsigned short* __restrict__ Ob)
{
  __shared__ __align__(16) unsigned short Buf[4][64*64];

  const int t    = threadIdx.x;
  const int lane = t & 63;
  const int w    = t >> 6;
  const int l15  = lane & 15;
  const int quad = lane >> 4;

  // XCD-grouping remap (validated R10: FETCH 139->24.6 MB)
  const int id   = blockIdx.x + (int)gridDim.x * blockIdx.y;
  const int r_   = id & 7;
  const int j_   = id >> 3;
  const int bh   = r_*8 + (j_ >> 4);
  const int qt   = j_ & 15;
  const int b    = bh >> 4, h = bh & 15;
  const int q0   = qt * 128;
  const int gbase = t & ~63;

  const size_t headoff = ((size_t)b*SEQ)*DM + (size_t)h*HD;
  const unsigned short* Qh = Qb + headoff;
  const unsigned short* Kh = Kb + headoff;
  const unsigned short* Vh = Vb + headoff;

  const int jp   = (t & 31) * 2;
  const int seg  = t >> 5;
  const int slot0 = ((jp >> 5) & 1)*32 + ((jp >> 2) & 3)*8 + ((jp >> 4) & 1)*4 + (jp & 3);
  const unsigned short* vsrc = Vh + (size_t)jp*DM + seg*8;

  {
    unsigned short* Qlds = &Buf[2][0];
    #pragma unroll
    for (int i = 0; i < 4; ++i) {
      int gb  = i*256 + gbase;
      int g   = gb + lane;
      int row = g >> 3;
      int cg  = (g & 7) ^ (row & 7);
      gl_lds16(Qh + (size_t)(q0 + row)*DM + cg*8, (char*)Qlds + (size_t)gb*16);
    }
  }
  bf16x8 pvA0 = *(const bf16x8*)(vsrc);
  bf16x8 pvA1 = *(const bf16x8*)(vsrc + DM);
  bf16x8 pvB0 = *(const bf16x8*)(vsrc + 64*DM);
  bf16x8 pvB1 = *(const bf16x8*)(vsrc + 65*DM);
  __syncthreads();

  bf16x8 qfA[2], qfB[2];
  {
    const unsigned short* Qlds = &Buf[2][0];
    #pragma unroll
    for (int kk = 0; kk < 2; ++kk) {
      int rA  = w*32 + l15;
      int rB  = w*32 + 16 + l15;
      qfA[kk] = *(const bf16x8*)&Qlds[(rA*64 + kk*32 + quad*8) ^ ((rA & 7) << 3)];
      qfB[kk] = *(const bf16x8*)&Qlds[(rB*64 + kk*32 + quad*8) ^ ((rB & 7) << 3)];
    }
  }
  auto writeV = [&](const bf16x8& v0, const bf16x8& v1, unsigned short* dst) {
    #pragma unroll
    for (int e = 0; e < 8; ++e) {
      int d = seg*8 + e;
      unsigned int pk = (unsigned int)(unsigned short)v0[e]
                      | ((unsigned int)(unsigned short)v1[e] << 16);
      *(unsigned int*)&dst[(d*64 + slot0) ^ ((d & 7) << 3)] = pk;
    }
  };
  writeV(pvA0, pvA1, Buf[0]);
  writeV(pvB0, pvB1, Buf[1]);
  __syncthreads();

  auto stageK = [&](int kv0, unsigned short* dst) {
    #pragma unroll
    for (int i = 0; i < 2; ++i) {
      int gb  = i*256 + gbase;
      int g   = gb + lane;
      int row = g >> 3;
      int cg  = (g & 7) ^ (row & 7);
      gl_lds16(Kh + (size_t)(kv0 + row)*DM + cg*8, (char*)dst + (size_t)gb*16);
    }
  };
  stageK(0,  Buf[2]);
  stageK(64, Buf[3]);
  __syncthreads();

  float lA = 0.f, lB = 0.f;
  f32x4 oA[4] = {}, oB[4] = {};
  const f32x4 mseed = {-M0SHIFT, -M0SHIFT, -M0SHIFT, -M0SHIFT};

  auto tile = [&](const unsigned short* Kc, const unsigned short* Vc) {
    f32x4 sA[4] = {mseed, mseed, mseed, mseed};
    f32x4 sB[4] = {mseed, mseed, mseed, mseed};
    __builtin_amdgcn_s_setprio(1);
    #pragma unroll
    for (int kk = 0; kk < 2; ++kk) {
      #pragma unroll
      for (int nt = 0; nt < 4; ++nt) {
        int r  = nt*16 + l15;
        int hi = (r*64 + kk*32 + quad*8) ^ ((r & 7) << 3);
        bf16x8 kf = *(const bf16x8*)&Kc[hi];
        sA[nt] = __builtin_amdgcn_mfma_f32_16x16x32_bf16(kf, qfA[kk], sA[nt], 0, 0, 0);
        sB[nt] = __builtin_amdgcn_mfma_f32_16x16x32_bf16(kf, qfB[kk], sB[nt], 0, 0, 0);
      }
    }
    __builtin_amdgcn_s_setprio(0);

    union { bf16x8 v; unsigned int u[4]; } PA0, PA1, PB0, PB1;
    {
      float p[4][4]; float rs = 0.f;
      #pragma unroll
      for (int nt = 0; nt < 4; ++nt)
        #pragma unroll
        for (int j = 0; j < 4; ++j) { p[nt][j] = fexp2(sA[nt][j]); rs += p[nt][j]; }
      lA += rs;
      #pragma unroll
      for (int k2 = 0; k2 < 4; ++k2) {
        int nt = k2 >> 1, a = (k2 & 1)*2;
        asm("v_cvt_pk_bf16_f32 %0, %1, %2" : "=v"(PA0.u[k2]) : "v"(p[nt][a]), "v"(p[nt][a+1]));
        asm("v_cvt_pk_bf16_f32 %0, %1, %2" : "=v"(PA1.u[k2]) : "v"(p[2+nt][a]), "v"(p[2+nt][a+1]));
      }
    }
    {
      float p[4][4]; float rs = 0.f;
      #pragma unroll
      for (int nt = 0; nt < 4; ++nt)
        #pragma unroll
        for (int j = 0; j < 4; ++j) { p[nt][j] = fexp2(sB[nt][j]); rs += p[nt][j]; }
      lB += rs;
      #pragma unroll
      for (int k2 = 0; k2 < 4; ++k2) {
        int nt = k2 >> 1, a = (k2 & 1)*2;
        asm("v_cvt_pk_bf16_f32 %0, %1, %2" : "=v"(PB0.u[k2]) : "v"(p[nt][a]), "v"(p[nt][a+1]));
        asm("v_cvt_pk_bf16_f32 %0, %1, %2" : "=v"(PB1.u[k2]) : "v"(p[2+nt][a]), "v"(p[2+nt][a+1]));
      }
    }

    __builtin_amdgcn_s_setprio(1);
    #pragma unroll
    for (int ks = 0; ks < 2; ++ks) {
      bf16x8 pfA = ks ? PA1.v : PA0.v;
      bf16x8 pfB = ks ? PB1.v : PB0.v;
      #pragma unroll
      for (int dt = 0; dt < 4; ++dt) {
        int d  = dt*16 + l15;
        int hi = (d*64 + ks*32 + quad*8) ^ ((d & 7) << 3);
        bf16x8 vf = *(const bf16x8*)&Vc[hi];
        oA[dt] = __builtin_amdgcn_mfma_f32_16x16x32_bf16(vf, pfA, oA[dt], 0, 0, 0);
        oB[dt] = __builtin_amdgcn_mfma_f32_16x16x32_bf16(vf, pfB, oB[dt], 0, 0, 0);
      }
    }
    __builtin_amdgcn_s_setprio(0);
  };

  for (int tk = 0; tk < SEQ/64; tk += 2) {
    const bool pa = (tk + 2 < SEQ/64);
    const bool pb = (tk + 3 < SEQ/64);
    if (pa) {
      const unsigned short* s = vsrc + (size_t)(tk + 2)*64*DM;
      pvA0 = *(const bf16x8*)(s);
      pvA1 = *(const bf16x8*)(s + DM);
    }
    tile(Buf[2], Buf[0]);
    __syncthreads();
    if (pa) { stageK((tk + 2)*64, Buf[2]); writeV(pvA0, pvA1, Buf[0]); }
    if (pb) {
      const unsigned short* s = vsrc + (size_t)(tk + 3)*64*DM;
      pvB0 = *(const bf16x8*)(s);
      pvB1 = *(const bf16x8*)(s + DM);
    }
    tile(Buf[3], Buf[1]);
    __syncthreads();
    if (pb) { stageK((tk + 3)*64, Buf[3]); writeV(pvB0, pvB1, Buf[1]); }
  }

  {
    float la = lA, lb = lB;
    la += __shfl_xor(la, 16); la += __shfl_xor(la, 32);
    lb += __shfl_xor(lb, 16); lb += __shfl_xor(lb, 32);
    float rla = 1.0f / la, rlb = 1.0f / lb;
    int qrowA = q0 + w*32 + l15;
    int qrowB = qrowA + 16;
    #pragma unroll
    for (int dt = 0; dt < 4; ++dt) {
      ushort4 u;
      u.x = f2b(oA[dt][0]*rla); u.y = f2b(oA[dt][1]*rla);
      u.z = f2b(oA[dt][2]*rla); u.w = f2b(oA[dt][3]*rla);
      *(ushort4*)&Ob[headoff + (size_t)qrowA*DM + dt*16 + quad*4] = u;
      ushort4 v;
      v.x = f2b(oB[dt][0]*rlb); v.y = f2b(oB[dt][1]*rlb);
      v.z = f2b(oB[dt][2]*rlb); v.w = f2b(oB[dt][3]*rlb);
      *(ushort4*)&Ob[headoff + (size_t)qrowB*DM + dt*16 + quad*4] = v;
    }
  }
}

// ---------------------------------------------------------------------------
extern "C" void kernel_launch(void* const* d_in, const int* in_sizes, int n_in,
                              void* d_out, int out_size, void* d_ws, size_t ws_size,
                              hipStream_t stream) {
  const float* q  = (const float*)d_in[0];
  const float* k  = (const float*)d_in[1];
  const float* v  = (const float*)d_in[2];
  const float* Wq = (const float*)d_in[3];
  const float* bq = (const float*)d_in[4];
  const float* Wk = (const float*)d_in[5];
  const float* bk = (const float*)d_in[6];
  const float* Wv = (const float*)d_in[7];
  const float* bv = (const float*)d_in[8];
  const float* Wo = (const float*)d_in[9];
  const float* bo = (const float*)d_in[10];

  const size_t MD  = (size_t)MTOT * DM;
  const size_t WSZ = (size_t)DM * DM;
  unsigned short* ws = (unsigned short*)d_ws;

  dim3 blk(256);
  dim3 blk512(512);
  dim3 gproj(DM/128, MTOT/128);   // (8, 64)
  dim3 gattn(SEQ/128, B_SZ*NH);   // (16, 64)

  const size_t need_big = (6*MD + 4*WSZ) * 2;   // ~109 MB
  const size_t need_mid = (4*MD + 1*WSZ) * 2;   // ~69 MB

  if (ws_size >= need_big) {
    unsigned short* qB  = ws;            // [qB kB vB] stride MD
    unsigned short* kB  = ws + MD;
    unsigned short* vB  = ws + 2*MD;
    unsigned short* Qp  = ws + 3*MD;     // [Qp Kp Vp] stride MD
    unsigned short* Kp  = ws + 4*MD;
    unsigned short* Vp  = ws + 5*MD;
    unsigned short* WqB = ws + 6*MD;     // [WqB WkB WvB WoB] stride WSZ
    unsigned short* WoB = WqB + 3*WSZ;
    unsigned short* Cp  = qB;

    hipLaunchKernelGGL(conv7, dim3(1024,1,7), blk, 0, stream,
                       q, k, v, Wq, Wk, Wv, Wo,
                       qB, kB, vB, WqB, WqB + WSZ, WqB + 2*WSZ, WoB,
                       (int)MD, (int)WSZ);

    hipLaunchKernelGGL(gemm_qkv256, dim3(DM/128, MTOT/256, 3), blk512, 0, stream,
                       qB, WqB, bq, bk, bv, Qp, QS_LOG2E);

    hipLaunchKernelGGL(attn_fwd, gattn, blk, 0, stream, Qp, Kp, Vp, Cp);

    hipLaunchKernelGGL(gemm_o256, dim3(DM/128, MTOT/256), blk512, 0, stream,
                       Cp, WoB, bo, (float*)d_out);
  } else if (ws_size >= need_mid) {
    unsigned short* Qp  = ws;
    unsigned short* Kp  = ws + MD;
    unsigned short* Vp  = ws + 2*MD;
    unsigned short* Cp  = ws + 3*MD;
    unsigned short* WqB = Cp;
    unsigned short* WkB = Cp + WSZ;
    unsigned short* WvB = Cp + 2*WSZ;
    unsigned short* WoB = ws + 4*MD;

    hipLaunchKernelGGL(conv4, dim3(512,1,4), blk, 0, stream, Wq, Wk, Wv, Wo, WqB, WkB, WvB, WoB, (int)WSZ);

    hipLaunchKernelGGL((gemm_bias<1,0,0>), gproj, blk, 0, stream, (const void*)q, (const void*)WqB, bq, (void*)Qp, MTOT, DM, DM, QS_LOG2E);
    hipLaunchKernelGGL((gemm_bias<1,0,0>), gproj, blk, 0, stream, (const void*)k, (const void*)WkB, bk, (void*)Kp, MTOT, DM, DM, 1.0f);
    hipLaunchKernelGGL((gemm_bias<1,0,0>), gproj, blk, 0, stream, (const void*)v, (const void*)WvB, bv, (void*)Vp, MTOT, DM, DM, 1.0f);
    hipLaunchKernelGGL(attn_fwd, gattn, blk, 0, stream, Qp, Kp, Vp, Cp);
    hipLaunchKernelGGL((gemm_bias<0,0,1>), gproj, blk, 0, stream, (const void*)Cp, (const void*)WoB, bo, d_out, MTOT, DM, DM, 1.0f);
  } else {
    unsigned short* Qp = ws;
    unsigned short* Kp = ws + MD;
    unsigned short* Vp = ws + 2*MD;
    unsigned short* Cp = ws + 3*MD;

    hipLaunchKernelGGL((gemm_bias<1,1,0>), gproj, blk, 0, stream, (const void*)q, (const void*)Wq, bq, (void*)Qp, MTOT, DM, DM, QS_LOG2E);
    hipLaunchKernelGGL((gemm_bias<1,1,0>), gproj, blk, 0, stream, (const void*)k, (const void*)Wk, bk, (void*)Kp, MTOT, DM, DM, 1.0f);
    hipLaunchKernelGGL((gemm_bias<1,1,0>), gproj, blk, 0, stream, (const void*)v, (const void*)Wv, bv, (void*)Vp, MTOT, DM, DM, 1.0f);
    hipLaunchKernelGGL(attn_fwd, gattn, blk, 0, stream, Qp, Kp, Vp, Cp);
    hipLaunchKernelGGL((gemm_bias<0,1,1>), gproj, blk, 0, stream, (const void*)Cp, (const void*)Wo, bo, d_out, MTOT, DM, DM, 1.0f);
  }
}

// Round 12
// 204.690 us; speedup vs baseline: 1.1664x; 1.1664x over previous
//
#include <hip/hip_runtime.h>
#include <hip/hip_bf16.h>
#include <stdint.h>

#define B_SZ 4
#define SEQ  2048
#define DM   1024
#define NH   16
#define HD   64
#define MTOT (B_SZ*SEQ)          // 8192
#define QS_LOG2E 0.18033688011112042f
#define M0SHIFT  24.0f

typedef __attribute__((ext_vector_type(8))) short bf16x8;
typedef __attribute__((ext_vector_type(4))) float f32x4;

#if __has_builtin(__builtin_amdgcn_exp2f)
__device__ __forceinline__ float fexp2(float x) { return __builtin_amdgcn_exp2f(x); }
#else
__device__ __forceinline__ float fexp2(float x) {
  float r; asm("v_exp_f32 %0, %1" : "=v"(r) : "v"(x)); return r;
}
#endif

__device__ __forceinline__ unsigned short f2b(float f) {
  union { float f; unsigned int i; } v; v.f = f;
  unsigned int r = v.i + 0x7fffu + ((v.i >> 16) & 1u);
  return (unsigned short)(r >> 16);
}

#define GPTR __attribute__((address_space(1)))
#define LPTR __attribute__((address_space(3)))
__device__ __forceinline__ void gl_lds16(const void* g, void* l) {
  __builtin_amdgcn_global_load_lds((GPTR const unsigned int*)g,
                                   (LPTR unsigned int*)l, 16, 0, 0);
}

// ---------------- fused f32 -> bf16 bulk converts ---------------------------
__device__ __forceinline__ void conv_body(const float* __restrict__ in,
                                          unsigned short* __restrict__ out, int n) {
  int i = (blockIdx.x * 256 + threadIdx.x) * 8;
  int stride = gridDim.x * 256 * 8;
  for (; i < n; i += stride) {
    float4 x = *(const float4*)(in + i);
    float4 y = *(const float4*)(in + i + 4);
    ushort4 u0; u0.x = f2b(x.x); u0.y = f2b(x.y); u0.z = f2b(x.z); u0.w = f2b(x.w);
    ushort4 u1; u1.x = f2b(y.x); u1.y = f2b(y.y); u1.z = f2b(y.z); u1.w = f2b(y.w);
    *(ushort4*)(out + i)     = u0;
    *(ushort4*)(out + i + 4) = u1;
  }
}
__global__ __launch_bounds__(256) void conv7(
    const float* __restrict__ q, const float* __restrict__ k, const float* __restrict__ v,
    const float* __restrict__ Wq, const float* __restrict__ Wk,
    const float* __restrict__ Wv, const float* __restrict__ Wo,
    unsigned short* __restrict__ oq, unsigned short* __restrict__ ok,
    unsigned short* __restrict__ ov, unsigned short* __restrict__ oWq,
    unsigned short* __restrict__ oWk, unsigned short* __restrict__ oWv,
    unsigned short* __restrict__ oWo, int nAct, int nW) {
  const int z = blockIdx.z;
  const float* in = (z == 0) ? q : (z == 1) ? k : (z == 2) ? v
                  : (z == 3) ? Wq : (z == 4) ? Wk : (z == 5) ? Wv : Wo;
  unsigned short* out = (z == 0) ? oq : (z == 1) ? ok : (z == 2) ? ov
                      : (z == 3) ? oWq : (z == 4) ? oWk : (z == 5) ? oWv : oWo;
  conv_body(in, out, (z < 3) ? nAct : nW);
}
__global__ __launch_bounds__(256) void conv4(const float* __restrict__ a,
                                             const float* __restrict__ b,
                                             const float* __restrict__ c,
                                             const float* __restrict__ d,
                                             unsigned short* __restrict__ oa,
                                             unsigned short* __restrict__ ob,
                                             unsigned short* __restrict__ oc,
                                             unsigned short* __restrict__ od,
                                             int n) {
  const float* in = (blockIdx.z == 0) ? a : (blockIdx.z == 1) ? b
                  : (blockIdx.z == 2) ? c : d;
  unsigned short* out = (blockIdx.z == 0) ? oa : (blockIdx.z == 1) ? ob
                      : (blockIdx.z == 2) ? oc : od;
  conv_body(in, out, n);
}

// ---------------- LDS staging (XOR swizzle) ---------------------------------
// element(row,col) at lds[(row*64+col) ^ ((row&7)<<3)]
__device__ __forceinline__ void stage_glds(const unsigned short* __restrict__ src,
                                           int ld, char* lds, int t) {
  const int gbase = t & ~63;
  const int lane  = t & 63;
  #pragma unroll
  for (int i = 0; i < 4; ++i) {
    int gb  = i*256 + gbase;
    int g   = gb + lane;
    int row = g >> 3;
    int cg  = (g & 7) ^ (row & 7);
    gl_lds16(src + (size_t)row*ld + cg*8, lds + (size_t)gb*16);
  }
}
__device__ __forceinline__ void stage_f32(const float* __restrict__ src, int ld,
                                          unsigned short* lds, int t) {
  #pragma unroll
  for (int i = 0; i < 8; ++i) {
    int e   = i*1024 + t*4;
    int row = e >> 6;
    int c4  = (e >> 2) & 15;
    float4 f = *(const float4*)(src + (size_t)row*ld + c4*4);
    ushort4 u;
    u.x = f2b(f.x); u.y = f2b(f.y); u.z = f2b(f.z); u.w = f2b(f.w);
    int hi = (row*64 + c4*4) ^ ((row & 7) << 3);
    *(ushort4*)&lds[hi] = u;
  }
}

// ---------------------------------------------------------------------------
// 128^2-tile GEMM core (R10-validated): C[m,n] = (sum X*W^T + bias) * oscale
// ---------------------------------------------------------------------------
template<int OUTF32>
__device__ __forceinline__ void gemm_core_bb(
    const unsigned short* __restrict__ X, const unsigned short* __restrict__ W,
    const float* __restrict__ bias, void* __restrict__ C,
    float oscale, int m0, int n0, int t,
    unsigned short* As, unsigned short* Bs)
{
  const int lane = t & 63;
  const int w    = t >> 6;
  const int wm   = w >> 1, wn = w & 1;

  f32x4 acc[4][4] = {};

  for (int k0 = 0; k0 < DM; k0 += 64) {
    __syncthreads();
    stage_glds(X + (size_t)m0*DM + k0, DM, (char*)As, t);
    stage_glds(W + (size_t)n0*DM + k0, DM, (char*)Bs, t);
    __syncthreads();

    #pragma unroll
    for (int kk = 0; kk < 2; ++kk) {
      bf16x8 af[4], bfr[4];
      #pragma unroll
      for (int mt = 0; mt < 4; ++mt) {
        int r  = wm*64 + mt*16 + (lane & 15);
        int hi = (r*64 + kk*32 + (lane >> 4)*8) ^ ((r & 7) << 3);
        af[mt] = *(const bf16x8*)&As[hi];
      }
      #pragma unroll
      for (int nt = 0; nt < 4; ++nt) {
        int r  = wn*64 + nt*16 + (lane & 15);
        int hi = (r*64 + kk*32 + (lane >> 4)*8) ^ ((r & 7) << 3);
        bfr[nt] = *(const bf16x8*)&Bs[hi];
      }
      #pragma unroll
      for (int mt = 0; mt < 4; ++mt)
        #pragma unroll
        for (int nt = 0; nt < 4; ++nt)
          acc[mt][nt] = __builtin_amdgcn_mfma_f32_16x16x32_bf16(
              af[mt], bfr[nt], acc[mt][nt], 0, 0, 0);
    }
  }

  #pragma unroll
  for (int nt = 0; nt < 4; ++nt) {
    int col = n0 + wn*64 + nt*16 + (lane & 15);
    float bv = bias[col];
    #pragma unroll
    for (int mt = 0; mt < 4; ++mt) {
      #pragma unroll
      for (int j = 0; j < 4; ++j) {
        int rrow = m0 + wm*64 + mt*16 + (lane >> 4)*4 + j;
        float val = (acc[mt][nt][j] + bv) * oscale;
        if (OUTF32) ((float*)C)[(size_t)rrow*DM + col] = val;
        else        ((unsigned short*)C)[(size_t)rrow*DM + col] = f2b(val);
      }
    }
  }
}

// fused Q/K/V projection, grid (8, 64, 3) with XCD-grouping remap (T1):
// all 8 n-blocks of one (y,z) X-row-panel land on the same XCD.
__global__ __launch_bounds__(256, 2) void gemm_qkv(
    const unsigned short* __restrict__ Xb, const unsigned short* __restrict__ Wb,
    const float* __restrict__ b0, const float* __restrict__ b1,
    const float* __restrict__ b2, unsigned short* __restrict__ Cb, float os0)
{
  __shared__ __align__(16) unsigned short As[128*64];
  __shared__ __align__(16) unsigned short Bs[128*64];
  const int id = blockIdx.x + 8*blockIdx.y + 512*blockIdx.z;  // 0..1535
  const int r_ = id & 7;
  const int xn = (id >> 3) & 7;
  const int G  = (id >> 6)*8 + r_;    // 0..191, bijective
  const int y  = G & 63;
  const int z  = G >> 6;              // 0..2
  const size_t MD  = (size_t)MTOT * DM;
  const size_t WSZ = (size_t)DM * DM;
  const float* bias = (z == 0) ? b0 : (z == 1) ? b1 : b2;
  gemm_core_bb<0>(Xb + (size_t)z*MD, Wb + (size_t)z*WSZ, bias,
                  (void*)(Cb + (size_t)z*MD), (z == 0) ? os0 : 1.0f,
                  y * 128, xn * 128, threadIdx.x, As, Bs);
}

// O projection, grid (8, 64), f32 out, same XCD-grouping remap
__global__ __launch_bounds__(256, 2) void gemm_o128(
    const unsigned short* __restrict__ X, const unsigned short* __restrict__ W,
    const float* __restrict__ bias, float* __restrict__ C)
{
  __shared__ __align__(16) unsigned short As[128*64];
  __shared__ __align__(16) unsigned short Bs[128*64];
  const int id = blockIdx.x + 8*blockIdx.y;   // 0..511
  const int r_ = id & 7;
  const int xn = (id >> 3) & 7;
  const int y  = (id >> 6)*8 + r_;            // 0..63, bijective
  gemm_core_bb<1>(X, W, bias, (void*)C, 1.0f,
                  y * 128, xn * 128, threadIdx.x, As, Bs);
}

// general single GEMM (fallback paths), 128^2
template<int AF32, int BF32, int OUTF32>
__global__ __launch_bounds__(256, 2) void gemm_bias(
    const void* __restrict__ Xv,
    const void* __restrict__ Wv,
    const float* __restrict__ bias,
    void* __restrict__ Cout,
    int M, int N, int Kd, float oscale)
{
  __shared__ __align__(16) unsigned short As[128*64];
  __shared__ __align__(16) unsigned short Bs[128*64];
  const int t    = threadIdx.x;
  const int lane = t & 63;
  const int w    = t >> 6;
  const int wm   = w >> 1, wn = w & 1;
  const int m0   = blockIdx.y * 128;
  const int n0   = blockIdx.x * 128;

  f32x4 acc[4][4] = {};

  for (int k0 = 0; k0 < Kd; k0 += 64) {
    __syncthreads();
    if (AF32) stage_f32((const float*)Xv + (size_t)m0*Kd + k0, Kd, As, t);
    else      stage_glds((const unsigned short*)Xv + (size_t)m0*Kd + k0, Kd, (char*)As, t);
    if (BF32) stage_f32((const float*)Wv + (size_t)n0*Kd + k0, Kd, Bs, t);
    else      stage_glds((const unsigned short*)Wv + (size_t)n0*Kd + k0, Kd, (char*)Bs, t);
    __syncthreads();

    #pragma unroll
    for (int kk = 0; kk < 2; ++kk) {
      bf16x8 af[4], bfr[4];
      #pragma unroll
      for (int mt = 0; mt < 4; ++mt) {
        int r  = wm*64 + mt*16 + (lane & 15);
        int hi = (r*64 + kk*32 + (lane >> 4)*8) ^ ((r & 7) << 3);
        af[mt] = *(const bf16x8*)&As[hi];
      }
      #pragma unroll
      for (int nt = 0; nt < 4; ++nt) {
        int r  = wn*64 + nt*16 + (lane & 15);
        int hi = (r*64 + kk*32 + (lane >> 4)*8) ^ ((r & 7) << 3);
        bfr[nt] = *(const bf16x8*)&Bs[hi];
      }
      #pragma unroll
      for (int mt = 0; mt < 4; ++mt)
        #pragma unroll
        for (int nt = 0; nt < 4; ++nt)
          acc[mt][nt] = __builtin_amdgcn_mfma_f32_16x16x32_bf16(
              af[mt], bfr[nt], acc[mt][nt], 0, 0, 0);
    }
  }

  #pragma unroll
  for (int nt = 0; nt < 4; ++nt) {
    int col = n0 + wn*64 + nt*16 + (lane & 15);
    float bv = bias[col];
    #pragma unroll
    for (int mt = 0; mt < 4; ++mt) {
      #pragma unroll
      for (int j = 0; j < 4; ++j) {
        int rrow = m0 + wm*64 + mt*16 + (lane >> 4)*4 + j;
        float val = (acc[mt][nt][j] + bv) * oscale;
        if (OUTF32)
          ((float*)Cout)[(size_t)rrow*N + col] = val;
        else
          ((unsigned short*)Cout)[(size_t)rrow*N + col] = f2b(val);
      }
    }
  }
}

// ---------------------------------------------------------------------------
// Flash attention fwd (R10-validated: 97.7us, FETCH 24.6MB, VGPR=100).
// R12 micro: V-pack via v_perm_b32 (1 inst vs shift+or chain).
// ---------------------------------------------------------------------------
__global__ __launch_bounds__(256, 2) void attn_fwd(
    const unsigned short* __restrict__ Qb,
    const unsigned short* __restrict__ Kb,
    const unsigned short* __restrict__ Vb,
    unsigned short* __restrict__ Ob)
{
  __shared__ __align__(16) unsigned short Buf[4][64*64];

  const int t    = threadIdx.x;
  const int lane = t & 63;
  const int w    = t >> 6;
  const int l15  = lane & 15;
  const int quad = lane >> 4;

  // XCD-grouping remap (validated R10: FETCH 139->24.6 MB)
  const int id   = blockIdx.x + (int)gridDim.x * blockIdx.y;
  const int r_   = id & 7;
  const int j_   = id >> 3;
  const int bh   = r_*8 + (j_ >> 4);
  const int qt   = j_ & 15;
  const int b    = bh >> 4, h = bh & 15;
  const int q0   = qt * 128;
  const int gbase = t & ~63;

  const size_t headoff = ((size_t)b*SEQ)*DM + (size_t)h*HD;
  const unsigned short* Qh = Qb + headoff;
  const unsigned short* Kh = Kb + headoff;
  const unsigned short* Vh = Vb + headoff;

  const int jp   = (t & 31) * 2;
  const int seg  = t >> 5;
  const int slot0 = ((jp >> 5) & 1)*32 + ((jp >> 2) & 3)*8 + ((jp >> 4) & 1)*4 + (jp & 3);
  const unsigned short* vsrc = Vh + (size_t)jp*DM + seg*8;

  {
    unsigned short* Qlds = &Buf[2][0];
    #pragma unroll
    for (int i = 0; i < 4; ++i) {
      int gb  = i*256 + gbase;
      int g   = gb + lane;
      int row = g >> 3;
      int cg  = (g & 7) ^ (row & 7);
      gl_lds16(Qh + (size_t)(q0 + row)*DM + cg*8, (char*)Qlds + (size_t)gb*16);
    }
  }
  bf16x8 pvA0 = *(const bf16x8*)(vsrc);
  bf16x8 pvA1 = *(const bf16x8*)(vsrc + DM);
  bf16x8 pvB0 = *(const bf16x8*)(vsrc + 64*DM);
  bf16x8 pvB1 = *(const bf16x8*)(vsrc + 65*DM);
  __syncthreads();

  bf16x8 qfA[2], qfB[2];
  {
    const unsigned short* Qlds = &Buf[2][0];
    #pragma unroll
    for (int kk = 0; kk < 2; ++kk) {
      int rA  = w*32 + l15;
      int rB  = w*32 + 16 + l15;
      qfA[kk] = *(const bf16x8*)&Qlds[(rA*64 + kk*32 + quad*8) ^ ((rA & 7) << 3)];
      qfB[kk] = *(const bf16x8*)&Qlds[(rB*64 + kk*32 + quad*8) ^ ((rB & 7) << 3)];
    }
  }
  // V-pack: pk(e) = v0[e] | v1[e]<<16 == v_perm_b32(v1w, v0w, sel(h))
  // sel bytes 0-3 pick src1(v0w) bytes, 4-7 pick src0(v1w) bytes.
  auto writeV = [&](const bf16x8& v0, const bf16x8& v1, unsigned short* dst) {
    const unsigned int* v0w = (const unsigned int*)&v0;
    const unsigned int* v1w = (const unsigned int*)&v1;
    #pragma unroll
    for (int e = 0; e < 8; ++e) {
      int d = seg*8 + e;
      unsigned int pk = __builtin_amdgcn_perm(
          v1w[e >> 1], v0w[e >> 1],
          (e & 1) ? 0x07060302u : 0x05040100u);
      *(unsigned int*)&dst[(d*64 + slot0) ^ ((d & 7) << 3)] = pk;
    }
  };
  writeV(pvA0, pvA1, Buf[0]);
  writeV(pvB0, pvB1, Buf[1]);
  __syncthreads();

  auto stageK = [&](int kv0, unsigned short* dst) {
    #pragma unroll
    for (int i = 0; i < 2; ++i) {
      int gb  = i*256 + gbase;
      int g   = gb + lane;
      int row = g >> 3;
      int cg  = (g & 7) ^ (row & 7);
      gl_lds16(Kh + (size_t)(kv0 + row)*DM + cg*8, (char*)dst + (size_t)gb*16);
    }
  };
  stageK(0,  Buf[2]);
  stageK(64, Buf[3]);
  __syncthreads();

  float lA = 0.f, lB = 0.f;
  f32x4 oA[4] = {}, oB[4] = {};
  const f32x4 mseed = {-M0SHIFT, -M0SHIFT, -M0SHIFT, -M0SHIFT};

  auto tile = [&](const unsigned short* Kc, const unsigned short* Vc) {
    f32x4 sA[4] = {mseed, mseed, mseed, mseed};
    f32x4 sB[4] = {mseed, mseed, mseed, mseed};
    __builtin_amdgcn_s_setprio(1);
    #pragma unroll
    for (int kk = 0; kk < 2; ++kk) {
      #pragma unroll
      for (int nt = 0; nt < 4; ++nt) {
        int r  = nt*16 + l15;
        int hi = (r*64 + kk*32 + quad*8) ^ ((r & 7) << 3);
        bf16x8 kf = *(const bf16x8*)&Kc[hi];
        sA[nt] = __builtin_amdgcn_mfma_f32_16x16x32_bf16(kf, qfA[kk], sA[nt], 0, 0, 0);
        sB[nt] = __builtin_amdgcn_mfma_f32_16x16x32_bf16(kf, qfB[kk], sB[nt], 0, 0, 0);
      }
    }
    __builtin_amdgcn_s_setprio(0);

    union { bf16x8 v; unsigned int u[4]; } PA0, PA1, PB0, PB1;
    {
      float p[4][4]; float rs = 0.f;
      #pragma unroll
      for (int nt = 0; nt < 4; ++nt)
        #pragma unroll
        for (int j = 0; j < 4; ++j) { p[nt][j] = fexp2(sA[nt][j]); rs += p[nt][j]; }
      lA += rs;
      #pragma unroll
      for (int k2 = 0; k2 < 4; ++k2) {
        int nt = k2 >> 1, a = (k2 & 1)*2;
        asm("v_cvt_pk_bf16_f32 %0, %1, %2" : "=v"(PA0.u[k2]) : "v"(p[nt][a]), "v"(p[nt][a+1]));
        asm("v_cvt_pk_bf16_f32 %0, %1, %2" : "=v"(PA1.u[k2]) : "v"(p[2+nt][a]), "v"(p[2+nt][a+1]));
      }
    }
    {
      float p[4][4]; float rs = 0.f;
      #pragma unroll
      for (int nt = 0; nt < 4; ++nt)
        #pragma unroll
        for (int j = 0; j < 4; ++j) { p[nt][j] = fexp2(sB[nt][j]); rs += p[nt][j]; }
      lB += rs;
      #pragma unroll
      for (int k2 = 0; k2 < 4; ++k2) {
        int nt = k2 >> 1, a = (k2 & 1)*2;
        asm("v_cvt_pk_bf16_f32 %0, %1, %2" : "=v"(PB0.u[k2]) : "v"(p[nt][a]), "v"(p[nt][a+1]));
        asm("v_cvt_pk_bf16_f32 %0, %1, %2" : "=v"(PB1.u[k2]) : "v"(p[2+nt][a]), "v"(p[2+nt][a+1]));
      }
    }

    __builtin_amdgcn_s_setprio(1);
    #pragma unroll
    for (int ks = 0; ks < 2; ++ks) {
      bf16x8 pfA = ks ? PA1.v : PA0.v;
      bf16x8 pfB = ks ? PB1.v : PB0.v;
      #pragma unroll
      for (int dt = 0; dt < 4; ++dt) {
        int d  = dt*16 + l15;
        int hi = (d*64 + ks*32 + quad*8) ^ ((d & 7) << 3);
        bf16x8 vf = *(const bf16x8*)&Vc[hi];
        oA[dt] = __builtin_amdgcn_mfma_f32_16x16x32_bf16(vf, pfA, oA[dt], 0, 0, 0);
        oB[dt] = __builtin_amdgcn_mfma_f32_16x16x32_bf16(vf, pfB, oB[dt], 0, 0, 0);
      }
    }
    __builtin_amdgcn_s_setprio(0);
  };

  for (int tk = 0; tk < SEQ/64; tk += 2) {
    const bool pa = (tk + 2 < SEQ/64);
    const bool pb = (tk + 3 < SEQ/64);
    if (pa) {
      const unsigned short* s = vsrc + (size_t)(tk + 2)*64*DM;
      pvA0 = *(const bf16x8*)(s);
      pvA1 = *(const bf16x8*)(s + DM);
    }
    tile(Buf[2], Buf[0]);
    __syncthreads();
    if (pa) { stageK((tk + 2)*64, Buf[2]); writeV(pvA0, pvA1, Buf[0]); }
    if (pb) {
      const unsigned short* s = vsrc + (size_t)(tk + 3)*64*DM;
      pvB0 = *(const bf16x8*)(s);
      pvB1 = *(const bf16x8*)(s + DM);
    }
    tile(Buf[3], Buf[1]);
    __syncthreads();
    if (pb) { stageK((tk + 3)*64, Buf[3]); writeV(pvB0, pvB1, Buf[1]); }
  }

  {
    float la = lA, lb = lB;
    la += __shfl_xor(la, 16); la += __shfl_xor(la, 32);
    lb += __shfl_xor(lb, 16); lb += __shfl_xor(lb, 32);
    float rla = 1.0f / la, rlb = 1.0f / lb;
    int qrowA = q0 + w*32 + l15;
    int qrowB = qrowA + 16;
    #pragma unroll
    for (int dt = 0; dt < 4; ++dt) {
      ushort4 u;
      u.x = f2b(oA[dt][0]*rla); u.y = f2b(oA[dt][1]*rla);
      u.z = f2b(oA[dt][2]*rla); u.w = f2b(oA[dt][3]*rla);
      *(ushort4*)&Ob[headoff + (size_t)qrowA*DM + dt*16 + quad*4] = u;
      ushort4 v;
      v.x = f2b(oB[dt][0]*rlb); v.y = f2b(oB[dt][1]*rlb);
      v.z = f2b(oB[dt][2]*rlb); v.w = f2b(oB[dt][3]*rlb);
      *(ushort4*)&Ob[headoff + (size_t)qrowB*DM + dt*16 + quad*4] = v;
    }
  }
}

// ---------------------------------------------------------------------------
extern "C" void kernel_launch(void* const* d_in, const int* in_sizes, int n_in,
                              void* d_out, int out_size, void* d_ws, size_t ws_size,
                              hipStream_t stream) {
  const float* q  = (const float*)d_in[0];
  const float* k  = (const float*)d_in[1];
  const float* v  = (const float*)d_in[2];
  const float* Wq = (const float*)d_in[3];
  const float* bq = (const float*)d_in[4];
  const float* Wk = (const float*)d_in[5];
  const float* bk = (const float*)d_in[6];
  const float* Wv = (const float*)d_in[7];
  const float* bv = (const float*)d_in[8];
  const float* Wo = (const float*)d_in[9];
  const float* bo = (const float*)d_in[10];

  const size_t MD  = (size_t)MTOT * DM;
  const size_t WSZ = (size_t)DM * DM;
  unsigned short* ws = (unsigned short*)d_ws;

  dim3 blk(256);
  dim3 gproj(DM/128, MTOT/128);   // (8, 64)
  dim3 gattn(SEQ/128, B_SZ*NH);   // (16, 64)

  const size_t need_big = (6*MD + 4*WSZ) * 2;   // ~109 MB
  const size_t need_mid = (4*MD + 1*WSZ) * 2;   // ~69 MB

  if (ws_size >= need_big) {
    unsigned short* qB  = ws;            // [qB kB vB] stride MD
    unsigned short* kB  = ws + MD;
    unsigned short* vB  = ws + 2*MD;
    unsigned short* Qp  = ws + 3*MD;     // [Qp Kp Vp] stride MD
    unsigned short* Kp  = ws + 4*MD;
    unsigned short* Vp  = ws + 5*MD;
    unsigned short* WqB = ws + 6*MD;     // [WqB WkB WvB WoB] stride WSZ
    unsigned short* WoB = WqB + 3*WSZ;
    unsigned short* Cp  = qB;

    hipLaunchKernelGGL(conv7, dim3(1024,1,7), blk, 0, stream,
                       q, k, v, Wq, Wk, Wv, Wo,
                       qB, kB, vB, WqB, WqB + WSZ, WqB + 2*WSZ, WoB,
                       (int)MD, (int)WSZ);

    hipLaunchKernelGGL(gemm_qkv, dim3(DM/128, MTOT/128, 3), blk, 0, stream,
                       qB, WqB, bq, bk, bv, Qp, QS_LOG2E);

    hipLaunchKernelGGL(attn_fwd, gattn, blk, 0, stream, Qp, Kp, Vp, Cp);

    hipLaunchKernelGGL(gemm_o128, gproj, blk, 0, stream, Cp, WoB, bo, (float*)d_out);
  } else if (ws_size >= need_mid) {
    unsigned short* Qp  = ws;
    unsigned short* Kp  = ws + MD;
    unsigned short* Vp  = ws + 2*MD;
    unsigned short* Cp  = ws + 3*MD;
    unsigned short* WqB = Cp;
    unsigned short* WkB = Cp + WSZ;
    unsigned short* WvB = Cp + 2*WSZ;
    unsigned short* WoB = ws + 4*MD;

    hipLaunchKernelGGL(conv4, dim3(512,1,4), blk, 0, stream, Wq, Wk, Wv, Wo, WqB, WkB, WvB, WoB, (int)WSZ);

    hipLaunchKernelGGL((gemm_bias<1,0,0>), gproj, blk, 0, stream, (const void*)q, (const void*)WqB, bq, (void*)Qp, MTOT, DM, DM, QS_LOG2E);
    hipLaunchKernelGGL((gemm_bias<1,0,0>), gproj, blk, 0, stream, (const void*)k, (const void*)WkB, bk, (void*)Kp, MTOT, DM, DM, 1.0f);
    hipLaunchKernelGGL((gemm_bias<1,0,0>), gproj, blk, 0, stream, (const void*)v, (const void*)WvB, bv, (void*)Vp, MTOT, DM, DM, 1.0f);
    hipLaunchKernelGGL(attn_fwd, gattn, blk, 0, stream, Qp, Kp, Vp, Cp);
    hipLaunchKernelGGL((gemm_bias<0,0,1>), gproj, blk, 0, stream, (const void*)Cp, (const void*)WoB, bo, d_out, MTOT, DM, DM, 1.0f);
  } else {
    unsigned short* Qp = ws;
    unsigned short* Kp = ws + MD;
    unsigned short* Vp = ws + 2*MD;
    unsigned short* Cp = ws + 3*MD;

    hipLaunchKernelGGL((gemm_bias<1,1,0>), gproj, blk, 0, stream, (const void*)q, (const void*)Wq, bq, (void*)Qp, MTOT, DM, DM, QS_LOG2E);
    hipLaunchKernelGGL((gemm_bias<1,1,0>), gproj, blk, 0, stream, (const void*)k, (const void*)Wk, bk, (void*)Kp, MTOT, DM, DM, 1.0f);
    hipLaunchKernelGGL((gemm_bias<1,1,0>), gproj, blk, 0, stream, (const void*)v, (const void*)Wv, bv, (void*)Vp, MTOT, DM, DM, 1.0f);
    hipLaunchKernelGGL(attn_fwd, gattn, blk, 0, stream, Qp, Kp, Vp, Cp);
    hipLaunchKernelGGL((gemm_bias<0,1,1>), gproj, blk, 0, stream, (const void*)Cp, (const void*)Wo, bo, d_out, MTOT, DM, DM, 1.0f);
  }
}